// Round 16
// baseline (183.858 us; speedup 1.0000x reference)
//
#include <hip/hip_runtime.h>
#include <hip/hip_bf16.h>
#include <math.h>

// AAGCN block, N=32 C=64 T=512 V=21 E=16 S=3.
// Round 16: k_y0 8t/block (grid 2048, 18.4KB LDS, halved frag state) for
// residency+backfill; k_M1red folded into k_s1's staging loop.

#define Nn 32
#define Cc 64
#define Tt 512
#define Vv 21
#define VP 24
#define Ss 3
#define EPSf 1e-5f
#define NCHUNK 16
#define SVV (Ss*Vv*Vv)   // 1323
#define KSTR 136

typedef __attribute__((ext_vector_type(8))) short short8;
typedef __attribute__((ext_vector_type(4))) float f32x4;

__device__ __forceinline__ float sigm(float x){ return 1.f/(1.f+expf(-x)); }
__device__ __forceinline__ float bf2f(unsigned short u){ return __uint_as_float((unsigned)u << 16); }
__device__ __forceinline__ unsigned short f2bf(float f){
    __hip_bfloat16 h = __float2bfloat16(f);
    return *reinterpret_cast<unsigned short*>(&h);
}

// ---------------- prep: pack wd + wa/wb + BN2 + BN1 params ----------------
__global__ __launch_bounds__(256) void k_prep(
    const float* __restrict__ wd, const float* __restrict__ bd,
    const float* __restrict__ g2, const float* __restrict__ b2,
    const float* __restrict__ mu2, const float* __restrict__ var2,
    const float* __restrict__ g1, const float* __restrict__ b1,
    const float* __restrict__ mu1, const float* __restrict__ var1,
    const float* __restrict__ wa, const float* __restrict__ wb,
    unsigned short* __restrict__ wdF, float4* __restrict__ bn2p,
    float2* __restrict__ bn1p, unsigned short* __restrict__ wawbF)
{
    int i = blockIdx.x*256 + threadIdx.x;
    if (i < 1536){
        int s  = i / 512;
        int w  = (i >> 7) & 3;
        int ks = (i >> 6) & 1;
        int l  = i & 63;
        int o  = 16*w + (l & 15);
        #pragma unroll
        for (int j = 0; j < 8; ++j){
            int c = 32*ks + 8*(l >> 4) + j;
            wdF[(size_t)i*8 + j] = f2bf(wd[(s*64 + o)*64 + c]);
        }
    }
    if (i < 768){
        int mt = i / 128;
        int ks = (i / 64) & 1;
        int l  = i & 63;
        int e  = l & 15;
        int g  = l >> 4;
        const float* src = (mt < 3) ? wa : wb;
        int s = (mt < 3) ? mt : mt - 3;
        #pragma unroll
        for (int j = 0; j < 8; ++j){
            int c = ks*32 + 8*g + j;
            wawbF[(size_t)i*8 + j] = f2bf(src[(s*16 + e)*64 + c]);
        }
    }
    if (i < 64){
        float bsum = bd[i] + bd[64+i] + bd[128+i];
        float sc = g2[i]*rsqrtf(var2[i]+EPSf);
        bn2p[i] = make_float4(bsum, sc, mu2[i], b2[i]);
    }
    if (i < 1344){
        float sc = g1[i]*rsqrtf(var1[i]+EPSf);
        bn1p[i] = make_float2(sc, b1[i] - mu1[i]*sc);
    }
}

// ---------------- materialize xbT (BN1 + raw-reshape shuffle), bf16 ----------------
__global__ __launch_bounds__(256) void k_xb(
    const float* __restrict__ x,
    const float2* __restrict__ bn1p,
    unsigned short* __restrict__ xbT)
{
    const int c0 = blockIdx.x;
    const int n  = blockIdx.y;
    const int tid = threadIdx.x;
    __shared__ unsigned short brick16[512*32];

    const float* xs = x + (size_t)(n*64 + c0)*10752;
    for (int i = tid; i < 2688; i += 256){
        float4 d = *reinterpret_cast<const float4*>(xs + i*4);
        #pragma unroll
        for (int e = 0; e < 4; ++e){
            int f = i*4 + e;
            int t = f / 21;
            int v = f - t*21;
            brick16[t*32 + ((v + 8*(t>>6)) & 31)] = f2bf(((const float*)&d)[e]);
        }
    }
    __syncthreads();

    if (tid < 192){
        const int agl = tid & 7;
        const int vp  = tid >> 3;
        const bool valid = (vp < 21);
        float scr[8], ofr[8];
        #pragma unroll
        for (int da = 0; da < 8; ++da){
            if (valid){
                float2 p = bn1p[vp*64 + agl*8 + da];
                scr[da] = p.x; ofr[da] = p.y;
            } else { scr[da] = 0.f; ofr[da] = 0.f; }
        }
        unsigned short* ob = xbT + ((size_t)(n*512 + c0)*24 + vp)*64 + agl*8;
        #pragma unroll
        for (int m = 0; m < 8; ++m){
            unsigned short pk[8];
            #pragma unroll
            for (int da = 0; da < 8; ++da){
                int row = agl*64 + da*8 + m;
                float xv = bf2f(brick16[row*32 + ((vp + 8*agl) & 31)]);
                float r = xv*scr[da] + ofr[da];
                pk[da] = valid ? f2bf(r) : (unsigned short)0;
            }
            *reinterpret_cast<uint4*>(ob + (size_t)m*64*24*64) =
                *reinterpret_cast<const uint4*>(pk);
        }
    }
}

// ---------------- attention pre-activation partials (MFMA) ----------------
__global__ __launch_bounds__(256) void k_attn(
    const unsigned short* __restrict__ xbT,
    const unsigned short* __restrict__ wawbF,
    const float* __restrict__ ba, const float* __restrict__ bb,
    float* __restrict__ part)
{
    const int chunk = blockIdx.x;
    const int n = blockIdx.y;
    const int tid = threadIdx.x;
    const int w  = tid >> 6;
    const int l  = tid & 63;
    const int g  = l >> 4;
    const int ln = l & 15;

    __shared__ unsigned short m1buf[3*32*KSTR];
    __shared__ unsigned short m2buf[3*32*KSTR];

    for (int i = tid; i < 3*8*KSTR; i += 256){
        int s = i / (8*KSTR), r = i % (8*KSTR);
        int off = (s*32 + 24)*KSTR + r;
        m1buf[off] = 0; m2buf[off] = 0;
    }

    short8 aF[6][2];
    float4 bias4[6];
    #pragma unroll
    for (int mt = 0; mt < 6; ++mt){
        #pragma unroll
        for (int ks = 0; ks < 2; ++ks)
            aF[mt][ks] = *reinterpret_cast<const short8*>(wawbF + (size_t)((mt*2+ks)*64 + l)*8);
        const float* bsrc = (mt < 3) ? (ba + mt*16) : (bb + (mt-3)*16);
        bias4[mt] = *reinterpret_cast<const float4*>(bsrc + 4*g);
    }

    f32x4 accB[3];
    #pragma unroll
    for (int q = 0; q < 3; ++q) accB[q] = (f32x4){0.f,0.f,0.f,0.f};

    int colv[3], colt[3];
    #pragma unroll
    for (int q = 0; q < 3; ++q){
        int col = (3*w + q)*16 + ln;
        colt[q] = col / 24;
        colv[q] = col % 24;
    }

    for (int st = 0; st < 4; ++st){
        const int tb = chunk*32 + st*8;
        #pragma unroll
        for (int q = 0; q < 3; ++q){
            const unsigned short* bp = xbT + ((size_t)(n*512 + tb + colt[q])*24 + colv[q])*64;
            short8 b0 = *reinterpret_cast<const short8*>(bp + 8*g);
            short8 b1 = *reinterpret_cast<const short8*>(bp + 32 + 8*g);
            #pragma unroll
            for (int mt = 0; mt < 6; ++mt){
                f32x4 c;
                c[0] = bias4[mt].x; c[1] = bias4[mt].y;
                c[2] = bias4[mt].z; c[3] = bias4[mt].w;
                c = __builtin_amdgcn_mfma_f32_16x16x32_bf16(aF[mt][0], b0, c, 0, 0, 0);
                c = __builtin_amdgcn_mfma_f32_16x16x32_bf16(aF[mt][1], b1, c, 0, 0, 0);
                unsigned short* dst = (mt < 3) ? m1buf : m2buf;
                int s = (mt < 3) ? mt : mt - 3;
                unsigned u0 = (unsigned)f2bf(c[0]) | ((unsigned)f2bf(c[1]) << 16);
                unsigned u1 = (unsigned)f2bf(c[2]) | ((unsigned)f2bf(c[3]) << 16);
                int off = (s*32 + colv[q])*KSTR + colt[q]*16 + 4*g;
                *reinterpret_cast<uint2*>(dst + off) = make_uint2(u0, u1);
            }
        }
        __syncthreads();
        #pragma unroll
        for (int q = 0; q < 3; ++q){
            int ct = 3*w + q;
            int s = ct >> 2, mtile = (ct >> 1) & 1, ntile = ct & 1;
            #pragma unroll
            for (int kk = 0; kk < 4; ++kk){
                short8 a = *reinterpret_cast<const short8*>(&m1buf[(s*32 + mtile*16 + ln)*KSTR + kk*32 + 8*g]);
                short8 b = *reinterpret_cast<const short8*>(&m2buf[(s*32 + ntile*16 + ln)*KSTR + kk*32 + 8*g]);
                accB[q] = __builtin_amdgcn_mfma_f32_16x16x32_bf16(a, b, accB[q], 0, 0, 0);
            }
        }
        __syncthreads();
    }

    float* pout = part + (size_t)(n*NCHUNK + chunk)*SVV;
    #pragma unroll
    for (int q = 0; q < 3; ++q){
        int ct = 3*w + q;
        int s = ct >> 2, mtile = (ct >> 1) & 1, ntile = ct & 1;
        int v = ntile*16 + ln;
        #pragma unroll
        for (int r = 0; r < 4; ++r){
            int u = mtile*16 + 4*g + r;
            if (u < 21 && v < 21)
                pout[s*441 + u*21 + v] = accB[q][r];
        }
    }
}

// ---------------- adj = PA + tanh(pre/8192)*alpha, fused into adjF pack ----------------
__global__ __launch_bounds__(256) void k_adjB(
    const float* __restrict__ part, const float* __restrict__ PA,
    const float* __restrict__ alpha, unsigned short* __restrict__ adjF)
{
    const int n = blockIdx.x;
    const int tid = threadIdx.x;
    __shared__ float adjs[SVV];
    const float al = alpha[0];
    for (int idx = tid; idx < SVV; idx += 256){
        float pre = 0.f;
        #pragma unroll
        for (int ch = 0; ch < NCHUNK; ++ch)
            pre += part[(size_t)(n*NCHUNK+ch)*SVV + idx];
        adjs[idx] = PA[idx] + tanhf(pre * (1.f/8192.f)) * al;
    }
    __syncthreads();
    for (int i = tid; i < 384; i += 256){
        int s = i / 128;
        int h = (i >> 6) & 1;
        int l = i & 63;
        int v = 16*h + (l & 15);
        unsigned short pk[8];
        #pragma unroll
        for (int j = 0; j < 8; ++j){
            int u = 8*(l >> 4) + j;
            float val = (u < 21 && v < 21) ? adjs[s*441 + u*21 + v] : 0.f;
            pk[j] = f2bf(val);
        }
        *reinterpret_cast<uint4*>(adjF + ((size_t)n*384 + i)*8) =
            *reinterpret_cast<const uint4*>(pk);
    }
}

// ---------------- graph conv + wd + BN2 + residual + relu (MFMA), 8 t/block ----------------
// writes y0bf [n][o][t][24] bf16 (pads zeroed) + per-block M1 partials.
__global__ __launch_bounds__(256) void k_y0(
    const unsigned short* __restrict__ xbT,
    const unsigned short* __restrict__ adjF,
    const unsigned short* __restrict__ wdF,
    const float4* __restrict__ bn2p,
    unsigned short* __restrict__ y0bf, float* __restrict__ M1P)
{
    const int n  = blockIdx.y;
    const int tb = blockIdx.x;          // 0..63, 8 t's each
    const int tid = threadIdx.x;
    const int w  = tid >> 6;
    const int l  = tid & 63;
    const int g  = l >> 4;
    const int ln = l & 15;

    __shared__ unsigned short xbuf[64*72];   // [c][2t x 32u], stride 144B
    __shared__ unsigned short zbuf[64*72];   // [col][64c],   stride 144B

    short8 badj[3][2];
    {
        const unsigned short* ap = adjF + (size_t)n*Ss*2*64*8;
        #pragma unroll
        for (int s = 0; s < 3; ++s)
            #pragma unroll
            for (int h = 0; h < 2; ++h)
                badj[s][h] = *reinterpret_cast<const short8*>(ap + ((s*2 + h)*64 + l)*8);
    }
    float4 bp[4];
    #pragma unroll
    for (int r = 0; r < 4; ++r) bp[r] = bn2p[16*w + 4*g + r];

    float m1a[4][2];
    #pragma unroll
    for (int r = 0; r < 4; ++r){ m1a[r][0] = 0.f; m1a[r][1] = 0.f; }

    unsigned short* yb = y0bf + (size_t)(n*64)*512*24;

    for (int tg = 0; tg < 4; ++tg){
        const int t0 = tb*8 + tg*2;
        if (tg) __syncthreads();
        if (tid < 128){
            int c = tid >> 1, t = tid & 1;
            *reinterpret_cast<uint4*>(&xbuf[c*72 + t*32 + 24]) = make_uint4(0u,0u,0u,0u);
        }
        // stage 2t x 64c x 24u = 384 uint4 reads, scalar-transposed writes
        for (int k = 0; k < 2; ++k){
            int i = tid + k*256;
            if (i < 384){
                int u = i % 24, t = (i/24) & 1, cg = i / 48;
                uint4 d = *reinterpret_cast<const uint4*>(
                    xbT + ((size_t)(n*512 + t0 + t)*24 + u)*64 + cg*8);
                const unsigned short* p = reinterpret_cast<const unsigned short*>(&d);
                #pragma unroll
                for (int dc = 0; dc < 8; ++dc)
                    xbuf[(cg*8 + dc)*72 + t*32 + u] = p[dc];
            }
        }
        __syncthreads();

        short8 ax[2];
        #pragma unroll
        for (int t = 0; t < 2; ++t)
            ax[t] = *reinterpret_cast<const short8*>(&xbuf[(16*w + ln)*72 + t*32 + 8*g]);

        f32x4 acc[4];
        #pragma unroll
        for (int ct = 0; ct < 4; ++ct) acc[ct] = (f32x4){0.f,0.f,0.f,0.f};

        for (int s = 0; s < 3; ++s){
            if (s) __syncthreads();
            f32x4 dz[4];
            #pragma unroll
            for (int ct = 0; ct < 4; ++ct)
                dz[ct] = __builtin_amdgcn_mfma_f32_16x16x32_bf16(
                             ax[ct>>1], badj[s][ct&1], (f32x4){0.f,0.f,0.f,0.f}, 0, 0, 0);
            #pragma unroll
            for (int ct = 0; ct < 4; ++ct){
                unsigned u0 = (unsigned)f2bf(dz[ct][0]) | ((unsigned)f2bf(dz[ct][1]) << 16);
                unsigned u1 = (unsigned)f2bf(dz[ct][2]) | ((unsigned)f2bf(dz[ct][3]) << 16);
                int col = (ct >> 1)*32 + (ct & 1)*16 + ln;
                *reinterpret_cast<uint2*>(&zbuf[col*72 + 16*w + 4*g]) = make_uint2(u0, u1);
            }
            __syncthreads();
            short8 aw0 = *reinterpret_cast<const short8*>(wdF + (size_t)(((s*4 + w)*2 + 0)*64 + l)*8);
            short8 aw1 = *reinterpret_cast<const short8*>(wdF + (size_t)(((s*4 + w)*2 + 1)*64 + l)*8);
            #pragma unroll
            for (int ct = 0; ct < 4; ++ct){
                int col = (ct >> 1)*32 + (ct & 1)*16 + ln;
                short8 b0 = *reinterpret_cast<const short8*>(&zbuf[col*72 + 0  + 8*g]);
                short8 b1 = *reinterpret_cast<const short8*>(&zbuf[col*72 + 32 + 8*g]);
                acc[ct] = __builtin_amdgcn_mfma_f32_16x16x32_bf16(aw0, b0, acc[ct], 0, 0, 0);
                acc[ct] = __builtin_amdgcn_mfma_f32_16x16x32_bf16(aw1, b1, acc[ct], 0, 0, 0);
            }
        }

        #pragma unroll
        for (int ct = 0; ct < 4; ++ct){
            const int t  = ct >> 1;
            const int h  = ct & 1;
            const int vp = h*16 + ln;
            if (vp < 24){
                #pragma unroll
                for (int r = 0; r < 4; ++r){
                    const int o = 16*w + 4*g + r;
                    unsigned short st = 0;
                    if (vp < 21){
                        float val = acc[ct][r] + bp[r].x;
                        val = (val - bp[r].z)*bp[r].y + bp[r].w;
                        val += bf2f(xbuf[o*72 + t*32 + vp]);
                        val = fmaxf(val, 0.f);
                        m1a[r][h] += val;
                        st = f2bf(val);
                    }
                    yb[((size_t)o*512 + t0 + t)*24 + vp] = st;
                }
            }
        }
    }

    #pragma unroll
    for (int h = 0; h < 2; ++h){
        const int vp = h*16 + ln;
        if (vp < 21){
            #pragma unroll
            for (int r = 0; r < 4; ++r){
                const int o = 16*w + 4*g + r;
                M1P[((size_t)(n*64 + tb))*1344 + o*21 + vp] = m1a[r][h];
            }
        }
    }
}

// ---------------- s1[n,v] = 1 + sigmoid(conv21((sum M1P)/T)) — fused reduce ----------------
__global__ __launch_bounds__(256) void k_s1(const float* __restrict__ M1P, const float* __restrict__ w_sa,
                     const float* __restrict__ b_sa, float* __restrict__ s1)
{
    const int n = blockIdx.x, tid = threadIdx.x;
    __shared__ float m1s[64][22];
    __shared__ float ws[64][22];
    __shared__ float red[12][21];
    for (int i = tid; i < 1344; i += 256){
        const float* p = M1P + (size_t)n*64*1344 + i;
        float s = 0.f;
        #pragma unroll 8
        for (int tb = 0; tb < 64; ++tb) s += p[(size_t)tb*1344];
        int c = i / 21, v = i % 21;
        m1s[c][v] = s;
        ws[c][v]  = w_sa[i];
    }
    __syncthreads();
    const int v = tid % 21;
    const int cg = tid / 21;
    float sum = 0.f;
    if (tid < 252){
        for (int c = cg; c < 64; c += 12){
            #pragma unroll
            for (int k = 0; k < 21; ++k){
                int src = v + k - 10;
                if (src >= 0 && src < 21)
                    sum += m1s[c][src] * ws[c][k];
            }
        }
        red[cg][v] = sum;
    }
    __syncthreads();
    if (tid < 21){
        float tot = b_sa[0];
        #pragma unroll
        for (int g = 0; g < 12; ++g) tot += red[g][tid] * (1.f/512.f);
        s1[n*Vv + tid] = 1.f + sigm(tot);
    }
}

// ---------------- M2[n,c,t] = sum_v y0bf*s1, LDS-staged row ----------------
__global__ __launch_bounds__(256) void k_M2(const unsigned short* __restrict__ y0bf,
                      const float* __restrict__ s1, float* __restrict__ M2)
{
    const int c = blockIdx.x, n = blockIdx.y, tid = threadIdx.x;
    __shared__ unsigned short row[512*24];
    __shared__ float s1s[21];
    if (tid < 21) s1s[tid] = s1[n*Vv + tid];
    const uint4* src = reinterpret_cast<const uint4*>(y0bf + (size_t)(n*64+c)*512*24);
    uint4* dst = reinterpret_cast<uint4*>(row);
    for (int i = tid; i < 1536; i += 256) dst[i] = src[i];
    __syncthreads();
    float* out = M2 + (size_t)(n*64+c)*512;
    for (int t = tid; t < 512; t += 256){
        float s = 0.f;
        #pragma unroll
        for (int v = 0; v < 21; ++v) s += bf2f(row[t*24+v]) * s1s[v];
        out[t] = s;
    }
}

// ---------------- s2[n,t] = 1 + sigmoid(conv9(M2/V)) — LDS-staged tiles ----------------
__global__ __launch_bounds__(256) void k_s2(const float* __restrict__ M2, const float* __restrict__ w_ta,
                      const float* __restrict__ b_ta, float* __restrict__ s2)
{
    const int n = blockIdx.y;
    const int t0 = blockIdx.x * 64;
    const int tid = threadIdx.x;
    __shared__ float m2s[64][72];
    __shared__ float wts[576];
    __shared__ float red[4][64];
    for (int i = tid; i < 64*72; i += 256){
        int c = i / 72, tt = i % 72;
        int src = t0 + tt - 4;
        m2s[c][tt] = (src >= 0 && src < 512) ? M2[(size_t)(n*64+c)*512 + src] : 0.f;
    }
    for (int i = tid; i < 576; i += 256) wts[i] = w_ta[i];
    __syncthreads();
    const int tl = tid & 63;
    const int cg = tid >> 6;
    float sum = 0.f;
    for (int c = cg*16; c < cg*16+16; ++c){
        #pragma unroll
        for (int k = 0; k < 9; ++k)
            sum += m2s[c][tl + k] * wts[c*9 + k];
    }
    red[cg][tl] = sum;
    __syncthreads();
    if (cg == 0){
        float tot = b_ta[0] + (red[0][tl]+red[1][tl]+red[2][tl]+red[3][tl]) * (1.f/21.f);
        s2[n*512 + t0 + tl] = 1.f + sigm(tot);
    }
}

// ---------------- sec[n,c] = (sum_t M2*s2)/(T*V) ----------------
__global__ __launch_bounds__(256) void k_sec(const float* __restrict__ M2, const float* __restrict__ s2,
                      float* __restrict__ sec)
{
    const int c = blockIdx.x, n = blockIdx.y, tid = threadIdx.x;
    const float* row = &M2[(size_t)(n*Cc+c)*Tt];
    const float* s2r = &s2[n*Tt];
    float acc = row[tid]*s2r[tid] + row[tid+256]*s2r[tid+256];
    #pragma unroll
    for (int off = 32; off > 0; off >>= 1)
        acc += __shfl_down(acc, off, 64);
    __shared__ float red[4];
    if ((tid & 63) == 0) red[tid >> 6] = acc;
    __syncthreads();
    if (tid == 0)
        sec[n*Cc + c] = (red[0]+red[1]+red[2]+red[3]) * (1.f/(512.f*21.f));
}

// ---------------- s3[n,c]: tiny FC from sec ----------------
__global__ __launch_bounds__(64) void k_s3fc(const float* __restrict__ sec,
                     const float* __restrict__ w1, const float* __restrict__ bf1,
                     const float* __restrict__ w2, const float* __restrict__ bf2,
                     float* __restrict__ s3)
{
    int n = blockIdx.x, c = threadIdx.x;
    __shared__ float secs[64];
    __shared__ float hh[32];
    secs[c] = sec[n*Cc + c];
    __syncthreads();
    if (c < 32){
        float h = bf1[c];
        #pragma unroll 8
        for (int k = 0; k < 64; ++k) h += w1[c*64+k]*secs[k];
        hh[c] = fmaxf(h, 0.f);
    }
    __syncthreads();
    float o = bf2[c];
    #pragma unroll 8
    for (int k = 0; k < 32; ++k) o += w2[c*32+k]*hh[k];
    s3[n*Cc + c] = 1.f + sigm(o);
}

// ---------------- final: y = relu(y0bf*s1*s2*s3), bf16-in f32-out ----------------
__global__ __launch_bounds__(256) void k_final(const unsigned short* __restrict__ y0bf,
    float* __restrict__ y,
    const float* __restrict__ s1, const float* __restrict__ s2, const float* __restrict__ s3)
{
    const int c = blockIdx.x, n = blockIdx.y, tid = threadIdx.x;
    __shared__ unsigned short row[512*24];
    __shared__ float s1s[21];
    __shared__ float s2s[512];
    if (tid < 21) s1s[tid] = s1[n*Vv + tid];
    for (int i = tid; i < 512; i += 256) s2s[i] = s2[n*512 + i];
    const uint4* src = reinterpret_cast<const uint4*>(y0bf + (size_t)(n*64+c)*512*24);
    uint4* dst = reinterpret_cast<uint4*>(row);
    for (int i = tid; i < 1536; i += 256) dst[i] = src[i];
    __syncthreads();
    const float sc3 = s3[n*Cc + c];
    float* base = y + (size_t)(n*Cc + c)*10752;
    for (int i = tid; i < 2688; i += 256){
        float r[4];
        #pragma unroll
        for (int e = 0; e < 4; ++e){
            int f = i*4 + e;
            int t = f / 21;
            int v = f - t*21;
            r[e] = fmaxf(bf2f(row[t*24+v]) * s1s[v] * s2s[t] * sc3, 0.f);
        }
        *reinterpret_cast<float4*>(base + i*4) = make_float4(r[0], r[1], r[2], r[3]);
    }
}

extern "C" void kernel_launch(void* const* d_in, const int* in_sizes, int n_in,
                              void* d_out, int out_size, void* d_ws, size_t ws_size,
                              hipStream_t stream)
{
    const float* x    = (const float*)d_in[0];
    const float* g1   = (const float*)d_in[2];
    const float* b1   = (const float*)d_in[3];
    const float* mu1  = (const float*)d_in[4];
    const float* var1 = (const float*)d_in[5];
    const float* PA   = (const float*)d_in[6];
    const float* alpha= (const float*)d_in[7];
    const float* wa   = (const float*)d_in[8];
    const float* ba   = (const float*)d_in[9];
    const float* wb   = (const float*)d_in[10];
    const float* bb   = (const float*)d_in[11];
    const float* wd   = (const float*)d_in[12];
    const float* bd   = (const float*)d_in[13];
    const float* g2   = (const float*)d_in[14];
    const float* b2   = (const float*)d_in[15];
    const float* mu2  = (const float*)d_in[16];
    const float* var2 = (const float*)d_in[17];
    const float* w_sa = (const float*)d_in[18];
    const float* b_sa = (const float*)d_in[19];
    const float* w_ta = (const float*)d_in[20];
    const float* b_ta = (const float*)d_in[21];
    const float* w_fc1= (const float*)d_in[22];
    const float* b_fc1= (const float*)d_in[23];
    const float* w_fc2= (const float*)d_in[24];
    const float* b_fc2= (const float*)d_in[25];

    // ws: xbT bf16 (50.33 MB) | f32 scratch (~19 MB incl. M1P 11MB) | y0bf bf16 (50.33 MB)
    unsigned short* xbT = (unsigned short*)d_ws;
    float* fws  = (float*)d_ws + 12582912;
    float* part = fws;                   // 677376
    float* M2   = part + 677376;         // 1048576
    float* s1   = M2   + 1048576;        // 672
    float* s2   = s1   + 672;            // 16384
    float* s3   = s2   + 16384;          // 2048
    float4* bn2p = (float4*)(s3 + 2048); // 256 f32
    unsigned short* wdF   = (unsigned short*)((float*)bn2p + 256);   // 12288 u16
    unsigned short* adjF  = wdF + 12288;                             // 98304 u16
    unsigned short* wawbF = adjF + 98304;                            // 6144 u16
    float* sec  = (float*)(wawbF + 6144);                            // 2048 f32
    float2* bn1p = (float2*)(sec + 2048);                            // 1344 f32x2
    float* M1P  = (float*)(bn1p + 1344);                             // 2752512 f32 (11 MB)
    unsigned short* y0bf = (unsigned short*)(M1P + 2752512);         // 25165824 u16
    float* y    = (float*)d_out;

    k_prep<<<6, 256, 0, stream>>>(wd, bd, g2, b2, mu2, var2, g1, b1, mu1, var1,
                                  wa, wb, wdF, bn2p, bn1p, wawbF);
    k_xb  <<<dim3(64, Nn), 256, 0, stream>>>(x, bn1p, xbT);
    k_attn<<<dim3(NCHUNK, Nn), 256, 0, stream>>>(xbT, wawbF, ba, bb, part);
    k_adjB<<<Nn, 256, 0, stream>>>(part, PA, alpha, adjF);
    k_y0  <<<dim3(64, Nn), 256, 0, stream>>>(xbT, adjF, wdF, bn2p, y0bf, M1P);
    k_s1  <<<Nn, 256, 0, stream>>>(M1P, w_sa, b_sa, s1);
    k_M2  <<<dim3(Cc, Nn), 256, 0, stream>>>(y0bf, s1, M2);
    k_s2  <<<dim3(8, Nn), 256, 0, stream>>>(M2, w_ta, b_ta, s2);
    k_sec <<<dim3(Cc, Nn), 256, 0, stream>>>(M2, s2, sec);
    k_s3fc<<<Nn, 64, 0, stream>>>(sec, w_fc1, b_fc1, w_fc2, b_fc2, s3);
    k_final<<<dim3(Cc, Nn), 256, 0, stream>>>(y0bf, y, s1, s2, s3);
}

// Round 17
// 169.173 us; speedup vs baseline: 1.0868x; 1.0868x over previous
//
#include <hip/hip_runtime.h>
#include <hip/hip_bf16.h>
#include <math.h>

// AAGCN block, N=32 C=64 T=512 V=21 E=16 S=3.
// Round 17: best-known recombination. k_y0 16t/block (round-15 version, bf16
// y0 out + M1 register partials); k_M1red fused into k_s1 (32 partials).
// 11 launches.

#define Nn 32
#define Cc 64
#define Tt 512
#define Vv 21
#define VP 24
#define Ss 3
#define EPSf 1e-5f
#define NCHUNK 16
#define SVV (Ss*Vv*Vv)   // 1323
#define KSTR 136

typedef __attribute__((ext_vector_type(8))) short short8;
typedef __attribute__((ext_vector_type(4))) float f32x4;

__device__ __forceinline__ float sigm(float x){ return 1.f/(1.f+expf(-x)); }
__device__ __forceinline__ float bf2f(unsigned short u){ return __uint_as_float((unsigned)u << 16); }
__device__ __forceinline__ unsigned short f2bf(float f){
    __hip_bfloat16 h = __float2bfloat16(f);
    return *reinterpret_cast<unsigned short*>(&h);
}

// ---------------- prep: pack wd + wa/wb + BN2 + BN1 params ----------------
__global__ __launch_bounds__(256) void k_prep(
    const float* __restrict__ wd, const float* __restrict__ bd,
    const float* __restrict__ g2, const float* __restrict__ b2,
    const float* __restrict__ mu2, const float* __restrict__ var2,
    const float* __restrict__ g1, const float* __restrict__ b1,
    const float* __restrict__ mu1, const float* __restrict__ var1,
    const float* __restrict__ wa, const float* __restrict__ wb,
    unsigned short* __restrict__ wdF, float4* __restrict__ bn2p,
    float2* __restrict__ bn1p, unsigned short* __restrict__ wawbF)
{
    int i = blockIdx.x*256 + threadIdx.x;
    if (i < 1536){
        int s  = i / 512;
        int w  = (i >> 7) & 3;
        int ks = (i >> 6) & 1;
        int l  = i & 63;
        int o  = 16*w + (l & 15);
        #pragma unroll
        for (int j = 0; j < 8; ++j){
            int c = 32*ks + 8*(l >> 4) + j;
            wdF[(size_t)i*8 + j] = f2bf(wd[(s*64 + o)*64 + c]);
        }
    }
    if (i < 768){
        int mt = i / 128;
        int ks = (i / 64) & 1;
        int l  = i & 63;
        int e  = l & 15;
        int g  = l >> 4;
        const float* src = (mt < 3) ? wa : wb;
        int s = (mt < 3) ? mt : mt - 3;
        #pragma unroll
        for (int j = 0; j < 8; ++j){
            int c = ks*32 + 8*g + j;
            wawbF[(size_t)i*8 + j] = f2bf(src[(s*16 + e)*64 + c]);
        }
    }
    if (i < 64){
        float bsum = bd[i] + bd[64+i] + bd[128+i];
        float sc = g2[i]*rsqrtf(var2[i]+EPSf);
        bn2p[i] = make_float4(bsum, sc, mu2[i], b2[i]);
    }
    if (i < 1344){
        float sc = g1[i]*rsqrtf(var1[i]+EPSf);
        bn1p[i] = make_float2(sc, b1[i] - mu1[i]*sc);
    }
}

// ---------------- materialize xbT (BN1 + raw-reshape shuffle), bf16 ----------------
__global__ __launch_bounds__(256) void k_xb(
    const float* __restrict__ x,
    const float2* __restrict__ bn1p,
    unsigned short* __restrict__ xbT)
{
    const int c0 = blockIdx.x;
    const int n  = blockIdx.y;
    const int tid = threadIdx.x;
    __shared__ unsigned short brick16[512*32];

    const float* xs = x + (size_t)(n*64 + c0)*10752;
    for (int i = tid; i < 2688; i += 256){
        float4 d = *reinterpret_cast<const float4*>(xs + i*4);
        #pragma unroll
        for (int e = 0; e < 4; ++e){
            int f = i*4 + e;
            int t = f / 21;
            int v = f - t*21;
            brick16[t*32 + ((v + 8*(t>>6)) & 31)] = f2bf(((const float*)&d)[e]);
        }
    }
    __syncthreads();

    if (tid < 192){
        const int agl = tid & 7;
        const int vp  = tid >> 3;
        const bool valid = (vp < 21);
        float scr[8], ofr[8];
        #pragma unroll
        for (int da = 0; da < 8; ++da){
            if (valid){
                float2 p = bn1p[vp*64 + agl*8 + da];
                scr[da] = p.x; ofr[da] = p.y;
            } else { scr[da] = 0.f; ofr[da] = 0.f; }
        }
        unsigned short* ob = xbT + ((size_t)(n*512 + c0)*24 + vp)*64 + agl*8;
        #pragma unroll
        for (int m = 0; m < 8; ++m){
            unsigned short pk[8];
            #pragma unroll
            for (int da = 0; da < 8; ++da){
                int row = agl*64 + da*8 + m;
                float xv = bf2f(brick16[row*32 + ((vp + 8*agl) & 31)]);
                float r = xv*scr[da] + ofr[da];
                pk[da] = valid ? f2bf(r) : (unsigned short)0;
            }
            *reinterpret_cast<uint4*>(ob + (size_t)m*64*24*64) =
                *reinterpret_cast<const uint4*>(pk);
        }
    }
}

// ---------------- attention pre-activation partials (MFMA) ----------------
__global__ __launch_bounds__(256) void k_attn(
    const unsigned short* __restrict__ xbT,
    const unsigned short* __restrict__ wawbF,
    const float* __restrict__ ba, const float* __restrict__ bb,
    float* __restrict__ part)
{
    const int chunk = blockIdx.x;
    const int n = blockIdx.y;
    const int tid = threadIdx.x;
    const int w  = tid >> 6;
    const int l  = tid & 63;
    const int g  = l >> 4;
    const int ln = l & 15;

    __shared__ unsigned short m1buf[3*32*KSTR];
    __shared__ unsigned short m2buf[3*32*KSTR];

    for (int i = tid; i < 3*8*KSTR; i += 256){
        int s = i / (8*KSTR), r = i % (8*KSTR);
        int off = (s*32 + 24)*KSTR + r;
        m1buf[off] = 0; m2buf[off] = 0;
    }

    short8 aF[6][2];
    float4 bias4[6];
    #pragma unroll
    for (int mt = 0; mt < 6; ++mt){
        #pragma unroll
        for (int ks = 0; ks < 2; ++ks)
            aF[mt][ks] = *reinterpret_cast<const short8*>(wawbF + (size_t)((mt*2+ks)*64 + l)*8);
        const float* bsrc = (mt < 3) ? (ba + mt*16) : (bb + (mt-3)*16);
        bias4[mt] = *reinterpret_cast<const float4*>(bsrc + 4*g);
    }

    f32x4 accB[3];
    #pragma unroll
    for (int q = 0; q < 3; ++q) accB[q] = (f32x4){0.f,0.f,0.f,0.f};

    int colv[3], colt[3];
    #pragma unroll
    for (int q = 0; q < 3; ++q){
        int col = (3*w + q)*16 + ln;
        colt[q] = col / 24;
        colv[q] = col % 24;
    }

    for (int st = 0; st < 4; ++st){
        const int tb = chunk*32 + st*8;
        #pragma unroll
        for (int q = 0; q < 3; ++q){
            const unsigned short* bp = xbT + ((size_t)(n*512 + tb + colt[q])*24 + colv[q])*64;
            short8 b0 = *reinterpret_cast<const short8*>(bp + 8*g);
            short8 b1 = *reinterpret_cast<const short8*>(bp + 32 + 8*g);
            #pragma unroll
            for (int mt = 0; mt < 6; ++mt){
                f32x4 c;
                c[0] = bias4[mt].x; c[1] = bias4[mt].y;
                c[2] = bias4[mt].z; c[3] = bias4[mt].w;
                c = __builtin_amdgcn_mfma_f32_16x16x32_bf16(aF[mt][0], b0, c, 0, 0, 0);
                c = __builtin_amdgcn_mfma_f32_16x16x32_bf16(aF[mt][1], b1, c, 0, 0, 0);
                unsigned short* dst = (mt < 3) ? m1buf : m2buf;
                int s = (mt < 3) ? mt : mt - 3;
                unsigned u0 = (unsigned)f2bf(c[0]) | ((unsigned)f2bf(c[1]) << 16);
                unsigned u1 = (unsigned)f2bf(c[2]) | ((unsigned)f2bf(c[3]) << 16);
                int off = (s*32 + colv[q])*KSTR + colt[q]*16 + 4*g;
                *reinterpret_cast<uint2*>(dst + off) = make_uint2(u0, u1);
            }
        }
        __syncthreads();
        #pragma unroll
        for (int q = 0; q < 3; ++q){
            int ct = 3*w + q;
            int s = ct >> 2, mtile = (ct >> 1) & 1, ntile = ct & 1;
            #pragma unroll
            for (int kk = 0; kk < 4; ++kk){
                short8 a = *reinterpret_cast<const short8*>(&m1buf[(s*32 + mtile*16 + ln)*KSTR + kk*32 + 8*g]);
                short8 b = *reinterpret_cast<const short8*>(&m2buf[(s*32 + ntile*16 + ln)*KSTR + kk*32 + 8*g]);
                accB[q] = __builtin_amdgcn_mfma_f32_16x16x32_bf16(a, b, accB[q], 0, 0, 0);
            }
        }
        __syncthreads();
    }

    float* pout = part + (size_t)(n*NCHUNK + chunk)*SVV;
    #pragma unroll
    for (int q = 0; q < 3; ++q){
        int ct = 3*w + q;
        int s = ct >> 2, mtile = (ct >> 1) & 1, ntile = ct & 1;
        int v = ntile*16 + ln;
        #pragma unroll
        for (int r = 0; r < 4; ++r){
            int u = mtile*16 + 4*g + r;
            if (u < 21 && v < 21)
                pout[s*441 + u*21 + v] = accB[q][r];
        }
    }
}

// ---------------- adj = PA + tanh(pre/8192)*alpha, fused into adjF pack ----------------
__global__ __launch_bounds__(256) void k_adjB(
    const float* __restrict__ part, const float* __restrict__ PA,
    const float* __restrict__ alpha, unsigned short* __restrict__ adjF)
{
    const int n = blockIdx.x;
    const int tid = threadIdx.x;
    __shared__ float adjs[SVV];
    const float al = alpha[0];
    for (int idx = tid; idx < SVV; idx += 256){
        float pre = 0.f;
        #pragma unroll
        for (int ch = 0; ch < NCHUNK; ++ch)
            pre += part[(size_t)(n*NCHUNK+ch)*SVV + idx];
        adjs[idx] = PA[idx] + tanhf(pre * (1.f/8192.f)) * al;
    }
    __syncthreads();
    for (int i = tid; i < 384; i += 256){
        int s = i / 128;
        int h = (i >> 6) & 1;
        int l = i & 63;
        int v = 16*h + (l & 15);
        unsigned short pk[8];
        #pragma unroll
        for (int j = 0; j < 8; ++j){
            int u = 8*(l >> 4) + j;
            float val = (u < 21 && v < 21) ? adjs[s*441 + u*21 + v] : 0.f;
            pk[j] = f2bf(val);
        }
        *reinterpret_cast<uint4*>(adjF + ((size_t)n*384 + i)*8) =
            *reinterpret_cast<const uint4*>(pk);
    }
}

// ---------------- graph conv + wd + BN2 + residual + relu (MFMA), 16 t/block ----------------
// writes y0bf [n][o][t][24] bf16 (pads zeroed) + per-block M1 partials.
__global__ __launch_bounds__(256) void k_y0(
    const unsigned short* __restrict__ xbT,
    const unsigned short* __restrict__ adjF,
    const unsigned short* __restrict__ wdF,
    const float4* __restrict__ bn2p,
    unsigned short* __restrict__ y0bf, float* __restrict__ M1P)
{
    const int n  = blockIdx.y;
    const int tb = blockIdx.x;
    const int tid = threadIdx.x;
    const int w  = tid >> 6;
    const int l  = tid & 63;
    const int g  = l >> 4;
    const int ln = l & 15;

    __shared__ unsigned short xbuf[64*136];
    __shared__ unsigned short zbuf[128*72];

    short8 badj[3][2];
    {
        const unsigned short* ap = adjF + (size_t)n*Ss*2*64*8;
        #pragma unroll
        for (int s = 0; s < 3; ++s)
            #pragma unroll
            for (int h = 0; h < 2; ++h)
                badj[s][h] = *reinterpret_cast<const short8*>(ap + ((s*2 + h)*64 + l)*8);
    }
    float4 bp[4];
    #pragma unroll
    for (int r = 0; r < 4; ++r) bp[r] = bn2p[16*w + 4*g + r];

    float m1a[4][2];
    #pragma unroll
    for (int r = 0; r < 4; ++r){ m1a[r][0] = 0.f; m1a[r][1] = 0.f; }

    unsigned short* yb = y0bf + (size_t)(n*64)*512*24;

    for (int tg = 0; tg < 4; ++tg){
        const int t0 = tb*16 + tg*4;
        if (tg) __syncthreads();
        {
            int c = tid >> 2, t = tid & 3;
            *reinterpret_cast<uint4*>(&xbuf[c*136 + t*32 + 24]) = make_uint4(0u,0u,0u,0u);
        }
        for (int k = 0; k < 3; ++k){
            int i = tid + k*256;
            int u = i % 24, t = (i/24) & 3, cg = i / 96;
            uint4 d = *reinterpret_cast<const uint4*>(
                xbT + ((size_t)(n*512 + t0 + t)*24 + u)*64 + cg*8);
            const unsigned short* p = reinterpret_cast<const unsigned short*>(&d);
            #pragma unroll
            for (int dc = 0; dc < 8; ++dc)
                xbuf[(cg*8 + dc)*136 + t*32 + u] = p[dc];
        }
        __syncthreads();

        short8 ax[4];
        #pragma unroll
        for (int t = 0; t < 4; ++t)
            ax[t] = *reinterpret_cast<const short8*>(&xbuf[(16*w + ln)*136 + t*32 + 8*g]);

        f32x4 acc[8];
        #pragma unroll
        for (int ct = 0; ct < 8; ++ct) acc[ct] = (f32x4){0.f,0.f,0.f,0.f};

        for (int s = 0; s < 3; ++s){
            if (s) __syncthreads();
            f32x4 dz[8];
            #pragma unroll
            for (int ct = 0; ct < 8; ++ct)
                dz[ct] = __builtin_amdgcn_mfma_f32_16x16x32_bf16(
                             ax[ct>>1], badj[s][ct&1], (f32x4){0.f,0.f,0.f,0.f}, 0, 0, 0);
            #pragma unroll
            for (int ct = 0; ct < 8; ++ct){
                unsigned u0 = (unsigned)f2bf(dz[ct][0]) | ((unsigned)f2bf(dz[ct][1]) << 16);
                unsigned u1 = (unsigned)f2bf(dz[ct][2]) | ((unsigned)f2bf(dz[ct][3]) << 16);
                int col = (ct >> 1)*32 + (ct & 1)*16 + ln;
                *reinterpret_cast<uint2*>(&zbuf[col*72 + 16*w + 4*g]) = make_uint2(u0, u1);
            }
            __syncthreads();
            short8 aw0 = *reinterpret_cast<const short8*>(wdF + (size_t)(((s*4 + w)*2 + 0)*64 + l)*8);
            short8 aw1 = *reinterpret_cast<const short8*>(wdF + (size_t)(((s*4 + w)*2 + 1)*64 + l)*8);
            #pragma unroll
            for (int ct = 0; ct < 8; ++ct){
                int col = (ct >> 1)*32 + (ct & 1)*16 + ln;
                short8 b0 = *reinterpret_cast<const short8*>(&zbuf[col*72 + 0  + 8*g]);
                short8 b1 = *reinterpret_cast<const short8*>(&zbuf[col*72 + 32 + 8*g]);
                acc[ct] = __builtin_amdgcn_mfma_f32_16x16x32_bf16(aw0, b0, acc[ct], 0, 0, 0);
                acc[ct] = __builtin_amdgcn_mfma_f32_16x16x32_bf16(aw1, b1, acc[ct], 0, 0, 0);
            }
        }

        #pragma unroll
        for (int ct = 0; ct < 8; ++ct){
            const int t  = ct >> 1;
            const int h  = ct & 1;
            const int vp = h*16 + ln;
            if (vp < 24){
                #pragma unroll
                for (int r = 0; r < 4; ++r){
                    const int o = 16*w + 4*g + r;
                    unsigned short st = 0;
                    if (vp < 21){
                        float val = acc[ct][r] + bp[r].x;
                        val = (val - bp[r].z)*bp[r].y + bp[r].w;
                        val += bf2f(xbuf[o*136 + t*32 + vp]);
                        val = fmaxf(val, 0.f);
                        m1a[r][h] += val;
                        st = f2bf(val);
                    }
                    yb[((size_t)o*512 + t0 + t)*24 + vp] = st;
                }
            }
        }
    }

    #pragma unroll
    for (int h = 0; h < 2; ++h){
        const int vp = h*16 + ln;
        if (vp < 21){
            #pragma unroll
            for (int r = 0; r < 4; ++r){
                const int o = 16*w + 4*g + r;
                M1P[((size_t)(n*32 + tb))*1344 + o*21 + vp] = m1a[r][h];
            }
        }
    }
}

// ---------------- s1[n,v] = 1 + sigmoid(conv21((sum M1P)/T)) — fused reduce ----------------
__global__ __launch_bounds__(256) void k_s1(const float* __restrict__ M1P, const float* __restrict__ w_sa,
                     const float* __restrict__ b_sa, float* __restrict__ s1)
{
    const int n = blockIdx.x, tid = threadIdx.x;
    __shared__ float m1s[64][22];
    __shared__ float ws[64][22];
    __shared__ float red[12][21];
    for (int i = tid; i < 1344; i += 256){
        const float* p = M1P + (size_t)n*32*1344 + i;
        float s = 0.f;
        #pragma unroll 8
        for (int tb = 0; tb < 32; ++tb) s += p[(size_t)tb*1344];
        int c = i / 21, v = i % 21;
        m1s[c][v] = s;
        ws[c][v]  = w_sa[i];
    }
    __syncthreads();
    const int v = tid % 21;
    const int cg = tid / 21;
    float sum = 0.f;
    if (tid < 252){
        for (int c = cg; c < 64; c += 12){
            #pragma unroll
            for (int k = 0; k < 21; ++k){
                int src = v + k - 10;
                if (src >= 0 && src < 21)
                    sum += m1s[c][src] * ws[c][k];
            }
        }
        red[cg][v] = sum;
    }
    __syncthreads();
    if (tid < 21){
        float tot = b_sa[0];
        #pragma unroll
        for (int g = 0; g < 12; ++g) tot += red[g][tid] * (1.f/512.f);
        s1[n*Vv + tid] = 1.f + sigm(tot);
    }
}

// ---------------- M2[n,c,t] = sum_v y0bf*s1, LDS-staged row ----------------
__global__ __launch_bounds__(256) void k_M2(const unsigned short* __restrict__ y0bf,
                      const float* __restrict__ s1, float* __restrict__ M2)
{
    const int c = blockIdx.x, n = blockIdx.y, tid = threadIdx.x;
    __shared__ unsigned short row[512*24];
    __shared__ float s1s[21];
    if (tid < 21) s1s[tid] = s1[n*Vv + tid];
    const uint4* src = reinterpret_cast<const uint4*>(y0bf + (size_t)(n*64+c)*512*24);
    uint4* dst = reinterpret_cast<uint4*>(row);
    for (int i = tid; i < 1536; i += 256) dst[i] = src[i];
    __syncthreads();
    float* out = M2 + (size_t)(n*64+c)*512;
    for (int t = tid; t < 512; t += 256){
        float s = 0.f;
        #pragma unroll
        for (int v = 0; v < 21; ++v) s += bf2f(row[t*24+v]) * s1s[v];
        out[t] = s;
    }
}

// ---------------- s2[n,t] = 1 + sigmoid(conv9(M2/V)) — LDS-staged tiles ----------------
__global__ __launch_bounds__(256) void k_s2(const float* __restrict__ M2, const float* __restrict__ w_ta,
                      const float* __restrict__ b_ta, float* __restrict__ s2)
{
    const int n = blockIdx.y;
    const int t0 = blockIdx.x * 64;
    const int tid = threadIdx.x;
    __shared__ float m2s[64][72];
    __shared__ float wts[576];
    __shared__ float red[4][64];
    for (int i = tid; i < 64*72; i += 256){
        int c = i / 72, tt = i % 72;
        int src = t0 + tt - 4;
        m2s[c][tt] = (src >= 0 && src < 512) ? M2[(size_t)(n*64+c)*512 + src] : 0.f;
    }
    for (int i = tid; i < 576; i += 256) wts[i] = w_ta[i];
    __syncthreads();
    const int tl = tid & 63;
    const int cg = tid >> 6;
    float sum = 0.f;
    for (int c = cg*16; c < cg*16+16; ++c){
        #pragma unroll
        for (int k = 0; k < 9; ++k)
            sum += m2s[c][tl + k] * wts[c*9 + k];
    }
    red[cg][tl] = sum;
    __syncthreads();
    if (cg == 0){
        float tot = b_ta[0] + (red[0][tl]+red[1][tl]+red[2][tl]+red[3][tl]) * (1.f/21.f);
        s2[n*512 + t0 + tl] = 1.f + sigm(tot);
    }
}

// ---------------- sec[n,c] = (sum_t M2*s2)/(T*V) ----------------
__global__ __launch_bounds__(256) void k_sec(const float* __restrict__ M2, const float* __restrict__ s2,
                      float* __restrict__ sec)
{
    const int c = blockIdx.x, n = blockIdx.y, tid = threadIdx.x;
    const float* row = &M2[(size_t)(n*Cc+c)*Tt];
    const float* s2r = &s2[n*Tt];
    float acc = row[tid]*s2r[tid] + row[tid+256]*s2r[tid+256];
    #pragma unroll
    for (int off = 32; off > 0; off >>= 1)
        acc += __shfl_down(acc, off, 64);
    __shared__ float red[4];
    if ((tid & 63) == 0) red[tid >> 6] = acc;
    __syncthreads();
    if (tid == 0)
        sec[n*Cc + c] = (red[0]+red[1]+red[2]+red[3]) * (1.f/(512.f*21.f));
}

// ---------------- s3[n,c]: tiny FC from sec ----------------
__global__ __launch_bounds__(64) void k_s3fc(const float* __restrict__ sec,
                     const float* __restrict__ w1, const float* __restrict__ bf1,
                     const float* __restrict__ w2, const float* __restrict__ bf2,
                     float* __restrict__ s3)
{
    int n = blockIdx.x, c = threadIdx.x;
    __shared__ float secs[64];
    __shared__ float hh[32];
    secs[c] = sec[n*Cc + c];
    __syncthreads();
    if (c < 32){
        float h = bf1[c];
        #pragma unroll 8
        for (int k = 0; k < 64; ++k) h += w1[c*64+k]*secs[k];
        hh[c] = fmaxf(h, 0.f);
    }
    __syncthreads();
    float o = bf2[c];
    #pragma unroll 8
    for (int k = 0; k < 32; ++k) o += w2[c*32+k]*hh[k];
    s3[n*Cc + c] = 1.f + sigm(o);
}

// ---------------- final: y = relu(y0bf*s1*s2*s3), bf16-in f32-out ----------------
__global__ __launch_bounds__(256) void k_final(const unsigned short* __restrict__ y0bf,
    float* __restrict__ y,
    const float* __restrict__ s1, const float* __restrict__ s2, const float* __restrict__ s3)
{
    const int c = blockIdx.x, n = blockIdx.y, tid = threadIdx.x;
    __shared__ unsigned short row[512*24];
    __shared__ float s1s[21];
    __shared__ float s2s[512];
    if (tid < 21) s1s[tid] = s1[n*Vv + tid];
    for (int i = tid; i < 512; i += 256) s2s[i] = s2[n*512 + i];
    const uint4* src = reinterpret_cast<const uint4*>(y0bf + (size_t)(n*64+c)*512*24);
    uint4* dst = reinterpret_cast<uint4*>(row);
    for (int i = tid; i < 1536; i += 256) dst[i] = src[i];
    __syncthreads();
    const float sc3 = s3[n*Cc + c];
    float* base = y + (size_t)(n*Cc + c)*10752;
    for (int i = tid; i < 2688; i += 256){
        float r[4];
        #pragma unroll
        for (int e = 0; e < 4; ++e){
            int f = i*4 + e;
            int t = f / 21;
            int v = f - t*21;
            r[e] = fmaxf(bf2f(row[t*24+v]) * s1s[v] * s2s[t] * sc3, 0.f);
        }
        *reinterpret_cast<float4*>(base + i*4) = make_float4(r[0], r[1], r[2], r[3]);
    }
}

extern "C" void kernel_launch(void* const* d_in, const int* in_sizes, int n_in,
                              void* d_out, int out_size, void* d_ws, size_t ws_size,
                              hipStream_t stream)
{
    const float* x    = (const float*)d_in[0];
    const float* g1   = (const float*)d_in[2];
    const float* b1   = (const float*)d_in[3];
    const float* mu1  = (const float*)d_in[4];
    const float* var1 = (const float*)d_in[5];
    const float* PA   = (const float*)d_in[6];
    const float* alpha= (const float*)d_in[7];
    const float* wa   = (const float*)d_in[8];
    const float* ba   = (const float*)d_in[9];
    const float* wb   = (const float*)d_in[10];
    const float* bb   = (const float*)d_in[11];
    const float* wd   = (const float*)d_in[12];
    const float* bd   = (const float*)d_in[13];
    const float* g2   = (const float*)d_in[14];
    const float* b2   = (const float*)d_in[15];
    const float* mu2  = (const float*)d_in[16];
    const float* var2 = (const float*)d_in[17];
    const float* w_sa = (const float*)d_in[18];
    const float* b_sa = (const float*)d_in[19];
    const float* w_ta = (const float*)d_in[20];
    const float* b_ta = (const float*)d_in[21];
    const float* w_fc1= (const float*)d_in[22];
    const float* b_fc1= (const float*)d_in[23];
    const float* w_fc2= (const float*)d_in[24];
    const float* b_fc2= (const float*)d_in[25];

    // ws: xbT bf16 (50.33 MB) | f32 scratch (~13 MB) | y0bf bf16 (50.33 MB)
    unsigned short* xbT = (unsigned short*)d_ws;
    float* fws  = (float*)d_ws + 12582912;
    float* part = fws;                   // 677376
    float* M2   = part + 677376;         // 1048576
    float* s1   = M2   + 1048576;        // 672
    float* s2   = s1   + 672;            // 16384
    float* s3   = s2   + 16384;          // 2048
    float4* bn2p = (float4*)(s3 + 2048); // 256 f32
    unsigned short* wdF   = (unsigned short*)((float*)bn2p + 256);   // 12288 u16
    unsigned short* adjF  = wdF + 12288;                             // 98304 u16
    unsigned short* wawbF = adjF + 98304;                            // 6144 u16
    float* sec  = (float*)(wawbF + 6144);                            // 2048 f32
    float2* bn1p = (float2*)(sec + 2048);                            // 1344 f32x2
    float* M1P  = (float*)(bn1p + 1344);                             // 1376256 f32
    unsigned short* y0bf = (unsigned short*)(M1P + 1376256);         // 25165824 u16
    float* y    = (float*)d_out;

    k_prep<<<6, 256, 0, stream>>>(wd, bd, g2, b2, mu2, var2, g1, b1, mu1, var1,
                                  wa, wb, wdF, bn2p, bn1p, wawbF);
    k_xb  <<<dim3(64, Nn), 256, 0, stream>>>(x, bn1p, xbT);
    k_attn<<<dim3(NCHUNK, Nn), 256, 0, stream>>>(xbT, wawbF, ba, bb, part);
    k_adjB<<<Nn, 256, 0, stream>>>(part, PA, alpha, adjF);
    k_y0  <<<dim3(32, Nn), 256, 0, stream>>>(xbT, adjF, wdF, bn2p, y0bf, M1P);
    k_s1  <<<Nn, 256, 0, stream>>>(M1P, w_sa, b_sa, s1);
    k_M2  <<<dim3(Cc, Nn), 256, 0, stream>>>(y0bf, s1, M2);
    k_s2  <<<dim3(8, Nn), 256, 0, stream>>>(M2, w_ta, b_ta, s2);
    k_sec <<<dim3(Cc, Nn), 256, 0, stream>>>(M2, s2, sec);
    k_s3fc<<<Nn, 64, 0, stream>>>(sec, w_fc1, b_fc1, w_fc2, b_fc2, s3);
    k_final<<<dim3(Cc, Nn), 256, 0, stream>>>(y0bf, y, s1, s2, s3);
}